// Round 1
// baseline (329.774 us; speedup 1.0000x reference)
//
#include <hip/hip_runtime.h>
#include <stdint.h>

#define T_TOK 8192   // B*S
#define DD    1024   // D
#define EN    8      // experts
#define BM    128
#define BN    128
#define BK    64

typedef __bf16 v8bf __attribute__((ext_vector_type(8)));
typedef float  v4f  __attribute__((ext_vector_type(4)));

__device__ __forceinline__ uint16_t f2b(float f) {
  uint32_t u = __builtin_bit_cast(uint32_t, f);
  u += 0x7FFFu + ((u >> 16) & 1u);          // round-to-nearest-even
  return (uint16_t)(u >> 16);
}

// ---------- Phase 1: gating (fp64 logits), routing lists, x -> bf16 ----------
__global__ __launch_bounds__(256) void gate_route_kernel(
    const float* __restrict__ x, const float* __restrict__ gw,
    const float* __restrict__ gb, uint16_t* __restrict__ xb,
    int* __restrict__ counts, int* __restrict__ lists) {
  __shared__ float sgw[DD * EN];   // 32 KB, [d][e]
  __shared__ float sx[4 * DD];     // 16 KB, 4 tokens
  const int tid = threadIdx.x;
#pragma unroll
  for (int i = 0; i < 32; ++i) sgw[i * 256 + tid] = gw[i * 256 + tid];
  const int t0 = blockIdx.x * 4;
  const float4* xg = (const float4*)(x + (size_t)t0 * DD);
  float4* sxv = (float4*)sx;
  ushort4* xbv = (ushort4*)(xb + (size_t)t0 * DD);
#pragma unroll
  for (int i = 0; i < 4; ++i) {
    float4 v = xg[i * 256 + tid];
    sxv[i * 256 + tid] = v;
    ushort4 h;
    h.x = f2b(v.x); h.y = f2b(v.y); h.z = f2b(v.z); h.w = f2b(v.w);
    xbv[i * 256 + tid] = h;
  }
  __syncthreads();
  const int wid = tid >> 6, lane = tid & 63;
  const int e = lane >> 3, dg = lane & 7;   // lane = (expert, d-group)
  const float* xrow = sx + wid * DD;
  double acc = 0.0;
  for (int k = 0; k < 128; ++k) {
    int d = dg + k * 8;
    acc += (double)xrow[d] * (double)sgw[d * 8 + e];   // 2-way bank alias: free
  }
#pragma unroll
  for (int off = 1; off < 8; off <<= 1) acc += __shfl_xor(acc, off);
  acc += (double)gb[e];
  double lg[8];
#pragma unroll
  for (int i = 0; i < 8; ++i) lg[i] = __shfl(acc, i * 8);
  if (lane == 0) {
    int e1 = 0; double m1 = lg[0];
#pragma unroll
    for (int i = 1; i < 8; ++i) if (lg[i] > m1) { m1 = lg[i]; e1 = i; }
    int e2 = 0; double m2 = -1.0e300;
#pragma unroll
    for (int i = 0; i < 8; ++i) if (i != e1 && lg[i] > m2) { m2 = lg[i]; e2 = i; }
    const int t = t0 + wid;
    int p1 = atomicAdd(&counts[e1], 1); lists[e1 * T_TOK + p1] = t;
    int p2 = atomicAdd(&counts[e2], 1); lists[e2 * T_TOK + p2] = t;
  }
}

// ---------- Phase 2: expert_w [e][d][f] fp32 -> Wt [e][f][d] bf16 ----------
__global__ __launch_bounds__(256) void wt_transpose_kernel(
    const float* __restrict__ w, uint16_t* __restrict__ wt) {
  __shared__ float tile[64][65];
  const int e = blockIdx.z;
  const int f0 = blockIdx.x * 64, d0 = blockIdx.y * 64;
  const float* wsrc = w + ((size_t)e << 20);
  uint16_t* wdst = wt + ((size_t)e << 20);
  const int r = threadIdx.x >> 6, c = threadIdx.x & 63;
#pragma unroll
  for (int i = 0; i < 16; ++i) {
    int row = i * 4 + r;
    tile[row][c] = wsrc[(size_t)(d0 + row) * DD + f0 + c];
  }
  __syncthreads();
#pragma unroll
  for (int i = 0; i < 16; ++i) {
    int frow = i * 4 + r;
    wdst[(size_t)(f0 + frow) * DD + d0 + c] = f2b(tile[c][frow]);
  }
}

// ---------- Phase 3: gathered per-expert GEMM, bf16 MFMA, scatter-atomic ----------
__global__ __launch_bounds__(256) void expert_gemm_kernel(
    const uint16_t* __restrict__ xb, const uint16_t* __restrict__ wt,
    const float* __restrict__ eb, const int* __restrict__ counts,
    const int* __restrict__ lists, float* __restrict__ out) {
  const int e = blockIdx.z;
  const int cnt = counts[e];
  const int m0 = blockIdx.y * BM;
  if (m0 >= cnt) return;
  const int n0 = blockIdx.x * BN;
  int rows = cnt - m0; if (rows > BM) rows = BM;

  __shared__ uint16_t sA[BM * BK];  // [m][k] linear (global_load_lds order)
  __shared__ uint16_t sB[BN * BK];  // [n][k] linear
  __shared__ int toks[BM];

  const int tid = threadIdx.x;
  if (tid < BM) {
    int rr = tid < rows ? tid : 0;
    toks[tid] = lists[e * T_TOK + m0 + rr];
  }
  __syncthreads();

  const int lane = tid & 63;
  const int wid = tid >> 6;
  const int wm = wid >> 1, wn = wid & 1;

  v4f acc[4][4];
#pragma unroll
  for (int i = 0; i < 4; ++i)
#pragma unroll
    for (int j = 0; j < 4; ++j) acc[i][j] = (v4f){0.f, 0.f, 0.f, 0.f};

  // Per-thread staging geometry: idx = i*256+tid; row = idx>>3; col8 = (idx&7)*8.
  const uint16_t* aptr[4];
  const uint16_t* bptr[4];
  const uint16_t* wte = wt + ((size_t)e << 20) + (size_t)n0 * DD;
#pragma unroll
  for (int i = 0; i < 4; ++i) {
    int idx = i * 256 + tid;
    int row = idx >> 3, c8 = (idx & 7) << 3;
    aptr[i] = xb + (size_t)toks[row] * DD + c8;
    bptr[i] = wte + (size_t)row * DD + c8;
  }

  for (int kt = 0; kt < DD / BK; ++kt) {
    const int k0 = kt * BK;
#pragma unroll
    for (int i = 0; i < 4; ++i) {
      int idx = i * 256 + tid;
      __builtin_amdgcn_global_load_lds(
          (const __attribute__((address_space(1))) uint32_t*)(aptr[i] + k0),
          (__attribute__((address_space(3))) uint32_t*)(sA + idx * 8), 16, 0, 0);
    }
#pragma unroll
    for (int i = 0; i < 4; ++i) {
      int idx = i * 256 + tid;
      __builtin_amdgcn_global_load_lds(
          (const __attribute__((address_space(1))) uint32_t*)(bptr[i] + k0),
          (__attribute__((address_space(3))) uint32_t*)(sB + idx * 8), 16, 0, 0);
    }
    __syncthreads();

#pragma unroll
    for (int kk = 0; kk < 2; ++kk) {
      v8bf af[4], bfr[4];
#pragma unroll
      for (int m = 0; m < 4; ++m)
        af[m] = *(const v8bf*)(sA + (wm * 64 + m * 16 + (lane & 15)) * BK +
                               kk * 32 + (lane >> 4) * 8);
#pragma unroll
      for (int n = 0; n < 4; ++n)
        bfr[n] = *(const v8bf*)(sB + (wn * 64 + n * 16 + (lane & 15)) * BK +
                                kk * 32 + (lane >> 4) * 8);
#pragma unroll
      for (int m = 0; m < 4; ++m)
#pragma unroll
        for (int n = 0; n < 4; ++n)
          acc[m][n] = __builtin_amdgcn_mfma_f32_16x16x32_bf16(
              af[m], bfr[n], acc[m][n], 0, 0, 0);
    }
    __syncthreads();
  }

  // Epilogue: C/D layout col=lane&15, row=(lane>>4)*4+j. Bias per contribution.
  const int col = lane & 15, rq = lane >> 4;
  float biasv[4];
#pragma unroll
  for (int n = 0; n < 4; ++n)
    biasv[n] = eb[e * DD + n0 + wn * 64 + n * 16 + col];
#pragma unroll
  for (int m = 0; m < 4; ++m) {
#pragma unroll
    for (int j = 0; j < 4; ++j) {
      int trow = wm * 64 + m * 16 + rq * 4 + j;
      if (trow < rows) {
        float* orow = out + (size_t)toks[trow] * DD + n0;
#pragma unroll
        for (int n = 0; n < 4; ++n) {
          int tcol = wn * 64 + n * 16 + col;
          atomicAdd(orow + tcol, acc[m][n][j] + biasv[n]);
        }
      }
    }
  }
}

extern "C" void kernel_launch(void* const* d_in, const int* in_sizes, int n_in,
                              void* d_out, int out_size, void* d_ws, size_t ws_size,
                              hipStream_t stream) {
  const float* x  = (const float*)d_in[0];   // [4,2048,1024] f32
  const float* gw = (const float*)d_in[1];   // [1024,8] f32
  const float* gb = (const float*)d_in[2];   // [8] f32
  const float* ew = (const float*)d_in[3];   // [8,1024,1024] f32
  const float* ebias = (const float*)d_in[4];// [8,1024] f32
  float* out = (float*)d_out;                // [4,2048,1024] f32

  uint8_t* ws = (uint8_t*)d_ws;
  int* counts = (int*)ws;                                   // 256 B
  int* lists  = (int*)(ws + 256);                           // 8*8192*4 = 256 KiB
  uint16_t* xb = (uint16_t*)(ws + 256 + 262144);            // 16 MiB bf16 x
  uint16_t* wt = (uint16_t*)(ws + 256 + 262144 + 16777216); // 16 MiB bf16 W^T

  hipMemsetAsync(counts, 0, 256, stream);
  hipMemsetAsync(d_out, 0, (size_t)out_size * sizeof(float), stream);

  gate_route_kernel<<<T_TOK / 4, 256, 0, stream>>>(x, gw, gb, xb, counts, lists);
  wt_transpose_kernel<<<dim3(16, 16, EN), 256, 0, stream>>>(ew, wt);
  expert_gemm_kernel<<<dim3(DD / BN, T_TOK / BM, EN), 256, 0, stream>>>(
      xb, wt, ebias, counts, lists, out);
}

// Round 2
// 177.594 us; speedup vs baseline: 1.8569x; 1.8569x over previous
//
#include <hip/hip_runtime.h>
#include <stdint.h>

#define T_TOK 8192   // B*S
#define DD    1024   // D
#define EN    8      // experts
#define BM    128
#define BN    128
#define BK    64
#define CPAD  16     // ints per expert counter slot (64 B -> one cache line each)

typedef __bf16 v8bf __attribute__((ext_vector_type(8)));
typedef float  v4f  __attribute__((ext_vector_type(4)));

__device__ __forceinline__ uint16_t f2b(float f) {
  uint32_t u = __builtin_bit_cast(uint32_t, f);
  u += 0x7FFFu + ((u >> 16) & 1u);          // round-to-nearest-even
  return (uint16_t)(u >> 16);
}

// ---------- Phase 1: gating (fp64 logits), block-aggregated routing, x -> bf16 ----------
// 256 blocks x 32 tokens. Per-wave token dot; per-block counting -> 8 padded atomics/block.
__global__ __launch_bounds__(256) void gate_route_kernel(
    const float* __restrict__ x, const float* __restrict__ gw,
    const float* __restrict__ gb, uint16_t* __restrict__ xb,
    int* __restrict__ counts, int* __restrict__ lists) {
  __shared__ float sgw[DD * EN];   // 32 KB, [d][e]
  __shared__ float sx[4][DD];      // 16 KB, one token per wave
  __shared__ int se1[32], se2[32]; // per-local-token top-2 picks
  const int tid = threadIdx.x;
#pragma unroll
  for (int i = 0; i < 32; ++i) sgw[i * 256 + tid] = gw[i * 256 + tid];
  const int t0 = blockIdx.x * 32;
  const int wid = tid >> 6, lane = tid & 63;
  const int e = lane >> 3, dg = lane & 7;   // lane = (expert, d-group)

  for (int r = 0; r < 8; ++r) {
    const int tt = t0 + wid * 8 + r;
    const float4* xg = (const float4*)(x + (size_t)tt * DD);
    float4* sxv = (float4*)sx[wid];
    ushort4* xbv = (ushort4*)(xb + (size_t)tt * DD);
#pragma unroll
    for (int i = 0; i < 4; ++i) {
      float4 v = xg[i * 64 + lane];
      sxv[i * 64 + lane] = v;
      ushort4 h;
      h.x = f2b(v.x); h.y = f2b(v.y); h.z = f2b(v.z); h.w = f2b(v.w);
      xbv[i * 64 + lane] = h;
    }
    __syncthreads();   // LDS visibility (cross-lane); waves run rounds in lockstep

    const float* xr = sx[wid];
    double a0 = 0.0, a1 = 0.0, a2 = 0.0, a3 = 0.0;
#pragma unroll 8
    for (int k = 0; k < 128; k += 4) {
      int d = dg + k * 8;
      a0 += (double)xr[d]      * (double)sgw[d * 8 + e];
      a1 += (double)xr[d + 8]  * (double)sgw[(d + 8) * 8 + e];
      a2 += (double)xr[d + 16] * (double)sgw[(d + 16) * 8 + e];
      a3 += (double)xr[d + 24] * (double)sgw[(d + 24) * 8 + e];
    }
    double acc = (a0 + a1) + (a2 + a3);
#pragma unroll
    for (int off = 1; off < 8; off <<= 1) acc += __shfl_xor(acc, off);
    acc += (double)gb[e];
    double lg[8];
#pragma unroll
    for (int i = 0; i < 8; ++i) lg[i] = __shfl(acc, i * 8);
    if (lane == 0) {
      int e1 = 0; double m1 = lg[0];
#pragma unroll
      for (int i = 1; i < 8; ++i) if (lg[i] > m1) { m1 = lg[i]; e1 = i; }
      int e2 = 0; double m2 = -1.0e300;
#pragma unroll
      for (int i = 0; i < 8; ++i) if (i != e1 && lg[i] > m2) { m2 = lg[i]; e2 = i; }
      se1[wid * 8 + r] = e1;
      se2[wid * 8 + r] = e2;
    }
    __syncthreads();
  }

  // Counting phase: one padded atomic per (block, expert).
  if (tid < EN) {
    int cnt = 0;
#pragma unroll
    for (int i = 0; i < 32; ++i) cnt += (se1[i] == tid) + (se2[i] == tid);
    int base = atomicAdd(&counts[tid * CPAD], cnt);
    int* dst = lists + tid * T_TOK;
    for (int i = 0; i < 32; ++i) {
      if (se1[i] == tid) dst[base++] = t0 + i;
      if (se2[i] == tid) dst[base++] = t0 + i;
    }
  }
}

// ---------- Phase 2: expert_w [e][d][f] fp32 -> Wt [e][f][d] bf16 ----------
__global__ __launch_bounds__(256) void wt_transpose_kernel(
    const float* __restrict__ w, uint16_t* __restrict__ wt) {
  __shared__ float tile[64][65];
  const int e = blockIdx.z;
  const int f0 = blockIdx.x * 64, d0 = blockIdx.y * 64;
  const float* wsrc = w + ((size_t)e << 20);
  uint16_t* wdst = wt + ((size_t)e << 20);
  const int r = threadIdx.x >> 6, c = threadIdx.x & 63;
#pragma unroll
  for (int i = 0; i < 16; ++i) {
    int row = i * 4 + r;
    tile[row][c] = wsrc[(size_t)(d0 + row) * DD + f0 + c];
  }
  __syncthreads();
#pragma unroll
  for (int i = 0; i < 16; ++i) {
    int frow = i * 4 + r;
    wdst[(size_t)(f0 + frow) * DD + d0 + c] = f2b(tile[c][frow]);
  }
}

// ---------- Phase 3: gathered per-expert GEMM, bf16 MFMA, scatter-atomic ----------
__global__ __launch_bounds__(256) void expert_gemm_kernel(
    const uint16_t* __restrict__ xb, const uint16_t* __restrict__ wt,
    const float* __restrict__ eb, const int* __restrict__ counts,
    const int* __restrict__ lists, float* __restrict__ out) {
  const int e = blockIdx.z;
  const int cnt = counts[e * CPAD];
  const int m0 = blockIdx.y * BM;
  if (m0 >= cnt) return;
  const int n0 = blockIdx.x * BN;
  int rows = cnt - m0; if (rows > BM) rows = BM;

  __shared__ uint16_t sA[BM * BK];  // [m][k] linear (global_load_lds order)
  __shared__ uint16_t sB[BN * BK];  // [n][k] linear
  __shared__ int toks[BM];

  const int tid = threadIdx.x;
  if (tid < BM) {
    int rr = tid < rows ? tid : 0;
    toks[tid] = lists[e * T_TOK + m0 + rr];
  }
  __syncthreads();

  const int lane = tid & 63;
  const int wid = tid >> 6;
  const int wm = wid >> 1, wn = wid & 1;

  v4f acc[4][4];
#pragma unroll
  for (int i = 0; i < 4; ++i)
#pragma unroll
    for (int j = 0; j < 4; ++j) acc[i][j] = (v4f){0.f, 0.f, 0.f, 0.f};

  // Per-thread staging geometry: idx = i*256+tid; row = idx>>3; col8 = (idx&7)*8.
  const uint16_t* aptr[4];
  const uint16_t* bptr[4];
  const uint16_t* wte = wt + ((size_t)e << 20) + (size_t)n0 * DD;
#pragma unroll
  for (int i = 0; i < 4; ++i) {
    int idx = i * 256 + tid;
    int row = idx >> 3, c8 = (idx & 7) << 3;
    aptr[i] = xb + (size_t)toks[row] * DD + c8;
    bptr[i] = wte + (size_t)row * DD + c8;
  }

  for (int kt = 0; kt < DD / BK; ++kt) {
    const int k0 = kt * BK;
#pragma unroll
    for (int i = 0; i < 4; ++i) {
      int idx = i * 256 + tid;
      __builtin_amdgcn_global_load_lds(
          (const __attribute__((address_space(1))) uint32_t*)(aptr[i] + k0),
          (__attribute__((address_space(3))) uint32_t*)(sA + idx * 8), 16, 0, 0);
    }
#pragma unroll
    for (int i = 0; i < 4; ++i) {
      int idx = i * 256 + tid;
      __builtin_amdgcn_global_load_lds(
          (const __attribute__((address_space(1))) uint32_t*)(bptr[i] + k0),
          (__attribute__((address_space(3))) uint32_t*)(sB + idx * 8), 16, 0, 0);
    }
    __syncthreads();

#pragma unroll
    for (int kk = 0; kk < 2; ++kk) {
      v8bf af[4], bfr[4];
#pragma unroll
      for (int m = 0; m < 4; ++m)
        af[m] = *(const v8bf*)(sA + (wm * 64 + m * 16 + (lane & 15)) * BK +
                               kk * 32 + (lane >> 4) * 8);
#pragma unroll
      for (int n = 0; n < 4; ++n)
        bfr[n] = *(const v8bf*)(sB + (wn * 64 + n * 16 + (lane & 15)) * BK +
                                kk * 32 + (lane >> 4) * 8);
#pragma unroll
      for (int m = 0; m < 4; ++m)
#pragma unroll
        for (int n = 0; n < 4; ++n)
          acc[m][n] = __builtin_amdgcn_mfma_f32_16x16x32_bf16(
              af[m], bfr[n], acc[m][n], 0, 0, 0);
    }
    __syncthreads();
  }

  // Epilogue: C/D layout col=lane&15, row=(lane>>4)*4+j. Bias per contribution.
  const int col = lane & 15, rq = lane >> 4;
  float biasv[4];
#pragma unroll
  for (int n = 0; n < 4; ++n)
    biasv[n] = eb[e * DD + n0 + wn * 64 + n * 16 + col];
#pragma unroll
  for (int m = 0; m < 4; ++m) {
#pragma unroll
    for (int j = 0; j < 4; ++j) {
      int trow = wm * 64 + m * 16 + rq * 4 + j;
      if (trow < rows) {
        float* orow = out + (size_t)toks[trow] * DD + n0;
#pragma unroll
        for (int n = 0; n < 4; ++n) {
          int tcol = wn * 64 + n * 16 + col;
          atomicAdd(orow + tcol, acc[m][n][j] + biasv[n]);
        }
      }
    }
  }
}

extern "C" void kernel_launch(void* const* d_in, const int* in_sizes, int n_in,
                              void* d_out, int out_size, void* d_ws, size_t ws_size,
                              hipStream_t stream) {
  const float* x  = (const float*)d_in[0];   // [4,2048,1024] f32
  const float* gw = (const float*)d_in[1];   // [1024,8] f32
  const float* gb = (const float*)d_in[2];   // [8] f32
  const float* ew = (const float*)d_in[3];   // [8,1024,1024] f32
  const float* ebias = (const float*)d_in[4];// [8,1024] f32
  float* out = (float*)d_out;                // [4,2048,1024] f32

  uint8_t* ws = (uint8_t*)d_ws;
  int* counts = (int*)ws;                                   // 8*CPAD*4 = 512 B
  int* lists  = (int*)(ws + 512);                           // 8*8192*4 = 256 KiB
  uint16_t* xb = (uint16_t*)(ws + 512 + 262144);            // 16 MiB bf16 x
  uint16_t* wt = (uint16_t*)(ws + 512 + 262144 + 16777216); // 16 MiB bf16 W^T

  hipMemsetAsync(counts, 0, 512, stream);
  hipMemsetAsync(d_out, 0, (size_t)out_size * sizeof(float), stream);

  gate_route_kernel<<<T_TOK / 32, 256, 0, stream>>>(x, gw, gb, xb, counts, lists);
  wt_transpose_kernel<<<dim3(16, 16, EN), 256, 0, stream>>>(ew, wt);
  expert_gemm_kernel<<<dim3(DD / BN, T_TOK / BM, EN), 256, 0, stream>>>(
      xb, wt, ebias, counts, lists, out);
}